// Round 10
// baseline (376.160 us; speedup 1.0000x reference)
//
#include <hip/hip_runtime.h>

#define NNODE 50000
#define NEDGE 800000

typedef __attribute__((ext_vector_type(8))) short bf16x8;
typedef __attribute__((ext_vector_type(4))) float f32x4;

// workspace byte offsets
#define WB_QCB   0          // 64*64 bf16   qc + all folded biases
#define WB_WRTB  8192       // 64*64 bf16   (Wr@W1r)^T  [n][k]
#define WB_W2TB  16384      // 128*64 bf16  W2^T        [n][k]
#define WB_WEH   33024      // 64*64 fp32   We@W1h
#define WB_WET   49408      // 64*64 fp32   We@W1t
#define WB_NHB   65792      // 50000*64 bf16
#define WB_NTB   6465792    // 50000*64 bf16

__device__ inline ushort f2b(float x) {           // fp32 -> bf16 RNE (scalar, prep_small only)
    uint u = __float_as_uint(x);
    return (ushort)((u + 0x7fffu + ((u >> 16) & 1u)) >> 16);
}
// HW packed fp32x2 -> bf16x2 (RNE), 1 VALU op. lo -> bits[15:0], hi -> bits[31:16].
__device__ inline uint cvtpk(float lo, float hi) {
    uint r;
    asm("v_cvt_pk_bf16_f32 %0, %1, %2" : "=v"(r) : "v"(lo), "v"(hi));
    return r;
}
__device__ inline float bLo(uint u) { return __uint_as_float(u << 16); }
__device__ inline float bHi(uint u) { return __uint_as_float(u & 0xffff0000u); }

__device__ inline void stage64(float* dst, const float* __restrict__ src, int t) {
    #pragma unroll
    for (int i = 0; i < 4; ++i) {
        int f = t + i * 256;
        *(float4*)&dst[f * 4] = *(const float4*)&src[f * 4];
    }
}

// C[r0+j][c0+i] = sum_k A[r0+j][k]*B[k][c0+i]; A,B 64x64 row-major in LDS
__device__ inline void gemm64(const float* sA, const float* sB, int t, float acc[4][4]) {
    const int r0 = (t >> 4) * 4, c0 = (t & 15) * 4;
    #pragma unroll
    for (int j = 0; j < 4; ++j)
        #pragma unroll
        for (int i = 0; i < 4; ++i) acc[j][i] = 0.f;
    #pragma unroll 4
    for (int k = 0; k < 64; ++k) {
        float4 b = *(const float4*)&sB[k * 64 + c0];
        float bv[4] = {b.x, b.y, b.z, b.w};
        #pragma unroll
        for (int j = 0; j < 4; ++j) {
            float a = sA[(r0 + j) * 64 + k];
            #pragma unroll
            for (int i = 0; i < 4; ++i) acc[j][i] = fmaf(a, bv[i], acc[j][i]);
        }
    }
}

__global__ __launch_bounds__(256)
void prep_small(const float* __restrict__ Q,
                const float* __restrict__ Wq, const float* __restrict__ bq,
                const float* __restrict__ We, const float* __restrict__ be,
                const float* __restrict__ Wr, const float* __restrict__ br,
                const float* __restrict__ W1, const float* __restrict__ b1,
                const float* __restrict__ W2, char* __restrict__ wsb)
{
    __shared__ float sA[4096], sB[4096], sC[4096], sBias[64];
    const int t = threadIdx.x;
    const int bid = blockIdx.x;
    const int r0 = (t >> 4) * 4, c0 = (t & 15) * 4;

    if (bid == 0) {
        // Wqq = Wq@W1[0:64]; qc = Q@Wqq + (b1 + bq@W1q + be@(W1h+W1t) + br@W1r)
        stage64(sA, Wq, t); stage64(sB, W1, t);
        __syncthreads();
        float acc[4][4];
        gemm64(sA, sB, t, acc);
        #pragma unroll
        for (int j = 0; j < 4; ++j)
            *(float4*)&sC[(r0 + j) * 64 + c0] = make_float4(acc[j][0], acc[j][1], acc[j][2], acc[j][3]);
        if (t < 64) {
            float s = b1[t];
            for (int k = 0; k < 64; ++k) {
                s = fmaf(bq[k], W1[k * 64 + t], s);
                s = fmaf(be[k], W1[(64 + k) * 64 + t] + W1[(192 + k) * 64 + t], s);
                s = fmaf(br[k], W1[(128 + k) * 64 + t], s);
            }
            sBias[t] = s;
        }
        __syncthreads();
        stage64(sA, Q, t);
        __syncthreads();
        gemm64(sA, sC, t, acc);
        ushort* qcb = (ushort*)(wsb + WB_QCB);
        #pragma unroll
        for (int j = 0; j < 4; ++j) {
            ushort4 p;
            p.x = f2b(acc[j][0] + sBias[c0 + 0]);
            p.y = f2b(acc[j][1] + sBias[c0 + 1]);
            p.z = f2b(acc[j][2] + sBias[c0 + 2]);
            p.w = f2b(acc[j][3] + sBias[c0 + 3]);
            *(ushort4*)&qcb[(r0 + j) * 64 + c0] = p;
        }
    } else if (bid == 1 || bid == 2) {
        // Weh / Wet (fp32, consumed by prep_nodes)
        const float* w1seg = W1 + (bid == 1 ? 64 * 64 : 192 * 64);
        float* dst = (float*)(wsb + (bid == 1 ? WB_WEH : WB_WET));
        stage64(sA, We, t); stage64(sB, w1seg, t);
        __syncthreads();
        float acc[4][4];
        gemm64(sA, sB, t, acc);
        #pragma unroll
        for (int j = 0; j < 4; ++j)
            *(float4*)&dst[(r0 + j) * 64 + c0] = make_float4(acc[j][0], acc[j][1], acc[j][2], acc[j][3]);
    } else if (bid == 3) {
        // WrT = (Wr@W1r)^T, bf16
        stage64(sA, Wr, t); stage64(sB, W1 + 128 * 64, t);
        __syncthreads();
        float acc[4][4];
        gemm64(sA, sB, t, acc);
        ushort* wrtb = (ushort*)(wsb + WB_WRTB);
        #pragma unroll
        for (int j = 0; j < 4; ++j)
            #pragma unroll
            for (int i = 0; i < 4; ++i)
                wrtb[(c0 + i) * 64 + (r0 + j)] = f2b(acc[j][i]);
    } else {
        // W2^T bf16
        ushort* w2tb = (ushort*)(wsb + WB_W2TB);
        #pragma unroll
        for (int i = 0; i < 32; ++i) {
            int f = t + i * 256;           // f < 8192
            int k = f >> 7, n = f & 127;
            w2tb[n * 64 + k] = f2b(W2[f]);
        }
    }
}

__global__ __launch_bounds__(256)
void prep_nodes(const float* __restrict__ Xn, const char* __restrict__ wsb_c,
                char* __restrict__ wsb)
{
    __shared__ float sXT[64 * 68];
    __shared__ float sWeh[4096], sWet[4096];
    const int t = threadIdx.x;
    const int nbase = blockIdx.x * 64;
    const float* Weh = (const float*)(wsb_c + WB_WEH);
    const float* Wet = (const float*)(wsb_c + WB_WET);
    ushort* nhb = (ushort*)(wsb + WB_NHB);
    ushort* ntb = (ushort*)(wsb + WB_NTB);

    #pragma unroll
    for (int i = 0; i < 4; ++i) {
        int f = t + i * 256;
        int n = f >> 4, s4 = (f & 15) * 4;
        int gn = nbase + n;
        float4 v = make_float4(0.f, 0.f, 0.f, 0.f);
        if (gn < NNODE) v = *(const float4*)&Xn[gn * 64 + s4];
        sXT[(s4 + 0) * 68 + n] = v.x;
        sXT[(s4 + 1) * 68 + n] = v.y;
        sXT[(s4 + 2) * 68 + n] = v.z;
        sXT[(s4 + 3) * 68 + n] = v.w;
    }
    #pragma unroll
    for (int i = 0; i < 4; ++i) {
        int f = t + i * 256;
        *(float4*)&sWeh[f * 4] = *(const float4*)&Weh[f * 4];
        *(float4*)&sWet[f * 4] = *(const float4*)&Wet[f * 4];
    }
    __syncthreads();

    const int er = (t >> 4) * 4, cc = (t & 15) * 4;
    float ah[4][4], at[4][4];
    #pragma unroll
    for (int j = 0; j < 4; ++j)
        #pragma unroll
        for (int i = 0; i < 4; ++i) { ah[j][i] = 0.f; at[j][i] = 0.f; }
    #pragma unroll 4
    for (int k = 0; k < 64; ++k) {
        float4 a  = *(const float4*)&sXT[k * 68 + er];
        float4 bh = *(const float4*)&sWeh[k * 64 + cc];
        float4 bt = *(const float4*)&sWet[k * 64 + cc];
        float av[4] = {a.x, a.y, a.z, a.w};
        #pragma unroll
        for (int j = 0; j < 4; ++j) {
            ah[j][0] = fmaf(av[j], bh.x, ah[j][0]); ah[j][1] = fmaf(av[j], bh.y, ah[j][1]);
            ah[j][2] = fmaf(av[j], bh.z, ah[j][2]); ah[j][3] = fmaf(av[j], bh.w, ah[j][3]);
            at[j][0] = fmaf(av[j], bt.x, at[j][0]); at[j][1] = fmaf(av[j], bt.y, at[j][1]);
            at[j][2] = fmaf(av[j], bt.z, at[j][2]); at[j][3] = fmaf(av[j], bt.w, at[j][3]);
        }
    }
    #pragma unroll
    for (int j = 0; j < 4; ++j) {
        int n = nbase + er + j;
        if (n < NNODE) {
            uint2 ph, pt;
            ph.x = cvtpk(ah[j][0], ah[j][1]); ph.y = cvtpk(ah[j][2], ah[j][3]);
            pt.x = cvtpk(at[j][0], at[j][1]); pt.y = cvtpk(at[j][2], at[j][3]);
            *(uint2*)&nhb[n * 64 + cc] = ph;
            *(uint2*)&ntb[n * 64 + cc] = pt;
        }
    }
}

// 4 tiles of 64 edges per block. Weight B-fragments live in REGISTERS
// (loaded per-lane from global once per block; L2-resident) -> no weight
// LDS re-reads in the tile loop (was 24 ds_read_b128/tile/thread = ~51%
// of DS cycles). All remaining LDS (X / gather-sum / h1) is wave-local,
// so the kernel is fully BARRIER-FREE. 2 blocks/CU (<=256 VGPR).
#define TILES_PER_BLK 4

__global__ __launch_bounds__(256, 2)
void edge_kernel(const float* __restrict__ Xe,
                 const int* __restrict__ EI,
                 const int* __restrict__ NB,
                 const float* __restrict__ b2,
                 const float* __restrict__ Wh,
                 const float* __restrict__ bh,
                 const char* __restrict__ wsb,
                 float* __restrict__ out)
{
    __shared__ ushort sX[64 * 72];     // X tile bf16; reused as H1 bf16 (wave-local rows)
    __shared__ ushort sG[64 * 72];     // gathered additive term, bf16 (wave-local rows)

    const int t = threadIdx.x;
    const ushort* qcb  = (const ushort*)(wsb + WB_QCB);
    const ushort* wrtb = (const ushort*)(wsb + WB_WRTB);
    const ushort* w2tb = (const ushort*)(wsb + WB_W2TB);
    const ushort* nhb  = (const ushort*)(wsb + WB_NHB);
    const ushort* ntb  = (const ushort*)(wsb + WB_NTB);

    const int lane = t & 63;
    const int w    = t >> 6;           // wave id = M-tile
    const int m    = lane & 15;
    const int qq   = lane >> 4;
    const int q8   = qq * 8;

    const int eg  = t >> 2;            // gather role: edge in tile (in [16w,16w+16))
    const int c0g = (t & 3) * 16;      // 16-col slice
    const int xrow = 16 * w + (lane >> 2);   // X-stage role: row (wave-local!)
    const int xsl  = lane & 3;               // float4-slice base

    // ---- weight B-fragments: global -> REGISTERS, once per block ----
    // Each lane loads exactly the fragment it feeds to MFMA every tile.
    bf16x8 wrF[4][2], w2F[8][2];
    #pragma unroll
    for (int nt = 0; nt < 4; ++nt) {
        wrF[nt][0] = *(const bf16x8*)&wrtb[(nt * 16 + m) * 64 + q8];
        wrF[nt][1] = *(const bf16x8*)&wrtb[(nt * 16 + m) * 64 + 32 + q8];
    }
    #pragma unroll
    for (int nt = 0; nt < 8; ++nt) {
        w2F[nt][0] = *(const bf16x8*)&w2tb[(nt * 16 + m) * 64 + q8];
        w2F[nt][1] = *(const bf16x8*)&w2tb[(nt * 16 + m) * 64 + 32 + q8];
    }
    // per-lane bias/head weights in registers (constant per block)
    float b2v[8], whv[8];
    #pragma unroll
    for (int nt = 0; nt < 8; ++nt) {
        b2v[nt] = b2[nt * 16 + m];
        whv[nt] = Wh[nt * 16 + m];
    }
    const float bh0 = bh[0];
    // NO __syncthreads anywhere: all LDS traffic below is wave-local.

    // per-tile load: gather chain + X rows -> registers
    auto load_tile = [&](int eb, uint4* g, float4* x) {
        int hd = EI[eb + eg];
        int tl = EI[NEDGE + eb + eg];
        int qi = NB[hd];
        g[0] = *(const uint4*)&qcb[qi * 64 + c0g];
        g[1] = *(const uint4*)&qcb[qi * 64 + c0g + 8];
        g[2] = *(const uint4*)&nhb[hd * 64 + c0g];
        g[3] = *(const uint4*)&nhb[hd * 64 + c0g + 8];
        g[4] = *(const uint4*)&ntb[tl * 64 + c0g];
        g[5] = *(const uint4*)&ntb[tl * 64 + c0g + 8];
        #pragma unroll
        for (int i = 0; i < 4; ++i)
            x[i] = *(const float4*)&Xe[(eb + xrow) * 64 + (xsl + 4 * i) * 4];
    };

    int ebase = blockIdx.x * (64 * TILES_PER_BLK);
    uint4  g[6];  float4 x[4];
    uint4  ng[6]; float4 nx[4];
    load_tile(ebase, g, x);

    #pragma unroll
    for (int tile = 0; tile < TILES_PER_BLK; ++tile) {
        // ---- gather-sum -> sG (wave-local rows) ----
        {
            uint pk[8];
            const uint* ua = (const uint*)&g[0];
            const uint* ub = (const uint*)&g[2];
            const uint* uc = (const uint*)&g[4];
            #pragma unroll
            for (int j = 0; j < 4; ++j) {
                float lo = bLo(ua[j]) + bLo(ub[j]) + bLo(uc[j]);
                float hi = bHi(ua[j]) + bHi(ub[j]) + bHi(uc[j]);
                pk[j] = cvtpk(lo, hi);
            }
            ua = (const uint*)&g[1]; ub = (const uint*)&g[3]; uc = (const uint*)&g[5];
            #pragma unroll
            for (int j = 0; j < 4; ++j) {
                float lo = bLo(ua[j]) + bLo(ub[j]) + bLo(uc[j]);
                float hi = bHi(ua[j]) + bHi(ub[j]) + bHi(uc[j]);
                pk[4 + j] = cvtpk(lo, hi);
            }
            *(uint4*)&sG[eg * 72 + c0g]     = make_uint4(pk[0], pk[1], pk[2], pk[3]);
            *(uint4*)&sG[eg * 72 + c0g + 8] = make_uint4(pk[4], pk[5], pk[6], pk[7]);
        }
        // ---- X -> bf16 LDS (wave-local rows, stride 72) ----
        #pragma unroll
        for (int i = 0; i < 4; ++i) {
            uint lo = cvtpk(x[i].x, x[i].y);
            uint hi = cvtpk(x[i].z, x[i].w);
            *(uint2*)&sX[xrow * 72 + (xsl + 4 * i) * 4] = make_uint2(lo, hi);
        }
        // ---- prefetch next tile (latency hidden under both MFMA phases) ----
        if (tile < TILES_PER_BLK - 1) load_tile(ebase + 64, ng, nx);

        // ---- h1 = relu(X@Wr' + g); write back into sX (same-wave RAW, in-order DS) ----
        bf16x8 a0 = *(const bf16x8*)&sX[(w * 16 + m) * 72 + q8];
        bf16x8 a1 = *(const bf16x8*)&sX[(w * 16 + m) * 72 + 32 + q8];
        f32x4 acc1[4];
        #pragma unroll
        for (int nt = 0; nt < 4; ++nt) {
            f32x4 c = {0.f, 0.f, 0.f, 0.f};
            c = __builtin_amdgcn_mfma_f32_16x16x32_bf16(a0, wrF[nt][0], c, 0, 0, 0);
            c = __builtin_amdgcn_mfma_f32_16x16x32_bf16(a1, wrF[nt][1], c, 0, 0, 0);
            acc1[nt] = c;
        }
        #pragma unroll
        for (int nt = 0; nt < 4; ++nt) {
            int c = nt * 16 + m;
            const int e0 = w * 16 + qq * 4;
            float v0 = fmaxf(acc1[nt][0] + __uint_as_float(((uint)sG[(e0 + 0) * 72 + c]) << 16), 0.f);
            float v1 = fmaxf(acc1[nt][1] + __uint_as_float(((uint)sG[(e0 + 1) * 72 + c]) << 16), 0.f);
            float v2 = fmaxf(acc1[nt][2] + __uint_as_float(((uint)sG[(e0 + 2) * 72 + c]) << 16), 0.f);
            float v3 = fmaxf(acc1[nt][3] + __uint_as_float(((uint)sG[(e0 + 3) * 72 + c]) << 16), 0.f);
            uint p01 = cvtpk(v0, v1);
            uint p23 = cvtpk(v2, v3);
            sX[(e0 + 0) * 72 + c] = (ushort)p01;
            sX[(e0 + 1) * 72 + c] = (ushort)(p01 >> 16);
            sX[(e0 + 2) * 72 + c] = (ushort)p23;
            sX[(e0 + 3) * 72 + c] = (ushort)(p23 >> 16);
        }

        // ---- h2 = relu(H1@W2 + b2); logit = h2@Wh + bh ----
        bf16x8 A0 = *(const bf16x8*)&sX[(w * 16 + m) * 72 + q8];
        bf16x8 A1 = *(const bf16x8*)&sX[(w * 16 + m) * 72 + 32 + q8];
        float part[4] = {0.f, 0.f, 0.f, 0.f};
        #pragma unroll
        for (int nt = 0; nt < 8; ++nt) {
            f32x4 c = {0.f, 0.f, 0.f, 0.f};
            c = __builtin_amdgcn_mfma_f32_16x16x32_bf16(A0, w2F[nt][0], c, 0, 0, 0);
            c = __builtin_amdgcn_mfma_f32_16x16x32_bf16(A1, w2F[nt][1], c, 0, 0, 0);
            #pragma unroll
            for (int r = 0; r < 4; ++r)
                part[r] = fmaf(fmaxf(c[r] + b2v[nt], 0.f), whv[nt], part[r]);
        }
        #pragma unroll
        for (int md = 1; md < 16; md <<= 1) {
            part[0] += __shfl_xor(part[0], md, 64);
            part[1] += __shfl_xor(part[1], md, 64);
            part[2] += __shfl_xor(part[2], md, 64);
            part[3] += __shfl_xor(part[3], md, 64);
        }
        if (m == 0) {
            float4 o;
            o.x = 1.f / (1.f + __expf(-(part[0] + bh0)));
            o.y = 1.f / (1.f + __expf(-(part[1] + bh0)));
            o.z = 1.f / (1.f + __expf(-(part[2] + bh0)));
            o.w = 1.f / (1.f + __expf(-(part[3] + bh0)));
            *(float4*)&out[ebase + w * 16 + qq * 4] = o;
        }

        if (tile < TILES_PER_BLK - 1) {
            ebase += 64;
            #pragma unroll
            for (int i = 0; i < 6; ++i) g[i] = ng[i];
            #pragma unroll
            for (int i = 0; i < 4; ++i) x[i] = nx[i];
        }
    }
}

extern "C" void kernel_launch(void* const* d_in, const int* in_sizes, int n_in,
                              void* d_out, int out_size, void* d_ws, size_t ws_size,
                              hipStream_t stream)
{
    const float* Q   = (const float*)d_in[0];
    const float* Xn  = (const float*)d_in[1];
    const float* Xe  = (const float*)d_in[2];
    const int*   EI  = (const int*)d_in[3];
    const int*   NB  = (const int*)d_in[4];
    const float* Wq  = (const float*)d_in[5];
    const float* bq  = (const float*)d_in[6];
    const float* We  = (const float*)d_in[7];
    const float* be  = (const float*)d_in[8];
    const float* Wr  = (const float*)d_in[9];
    const float* br  = (const float*)d_in[10];
    const float* W1  = (const float*)d_in[11];
    const float* b1  = (const float*)d_in[12];
    const float* W2  = (const float*)d_in[13];
    const float* b2  = (const float*)d_in[14];
    const float* Wh  = (const float*)d_in[15];
    const float* bh  = (const float*)d_in[16];
    float* out = (float*)d_out;
    char*  wsb = (char*)d_ws;

    prep_small<<<5, 256, 0, stream>>>(Q, Wq, bq, We, be, Wr, br, W1, b1, W2, wsb);
    prep_nodes<<<(NNODE + 63) / 64, 256, 0, stream>>>(Xn, wsb, wsb);
    edge_kernel<<<NEDGE / (64 * TILES_PER_BLK), 256, 0, stream>>>(Xe, EI, NB, b2, Wh, bh, wsb, out);
}

// Round 11
// 356.860 us; speedup vs baseline: 1.0541x; 1.0541x over previous
//
#include <hip/hip_runtime.h>

#define NNODE 50000
#define NEDGE 800000

typedef __attribute__((ext_vector_type(8))) short bf16x8;
typedef __attribute__((ext_vector_type(4))) float f32x4;

// workspace byte offsets
#define WB_QCB   0          // 64*64 bf16   qc + all folded biases
#define WB_WRTB  8192       // 64*64 bf16   (Wr@W1r)^T  [n][k]
#define WB_W2TB  16384      // 128*64 bf16  W2^T        [n][k]
#define WB_WEH   33024      // 64*64 fp32   We@W1h
#define WB_WET   49408      // 64*64 fp32   We@W1t
#define WB_NHB   65792      // 50000*64 bf16
#define WB_NTB   6465792    // 50000*64 bf16

__device__ inline ushort f2b(float x) {           // fp32 -> bf16 RNE (scalar, prep_small only)
    uint u = __float_as_uint(x);
    return (ushort)((u + 0x7fffu + ((u >> 16) & 1u)) >> 16);
}
// HW packed fp32x2 -> bf16x2 (RNE), 1 VALU op. lo -> bits[15:0], hi -> bits[31:16].
__device__ inline uint cvtpk(float lo, float hi) {
    uint r;
    asm("v_cvt_pk_bf16_f32 %0, %1, %2" : "=v"(r) : "v"(lo), "v"(hi));
    return r;
}
__device__ inline float bLo(uint u) { return __uint_as_float(u << 16); }
__device__ inline float bHi(uint u) { return __uint_as_float(u & 0xffff0000u); }

__device__ inline void stage64(float* dst, const float* __restrict__ src, int t) {
    #pragma unroll
    for (int i = 0; i < 4; ++i) {
        int f = t + i * 256;
        *(float4*)&dst[f * 4] = *(const float4*)&src[f * 4];
    }
}

// C[r0+j][c0+i] = sum_k A[r0+j][k]*B[k][c0+i]; A,B 64x64 row-major in LDS
__device__ inline void gemm64(const float* sA, const float* sB, int t, float acc[4][4]) {
    const int r0 = (t >> 4) * 4, c0 = (t & 15) * 4;
    #pragma unroll
    for (int j = 0; j < 4; ++j)
        #pragma unroll
        for (int i = 0; i < 4; ++i) acc[j][i] = 0.f;
    #pragma unroll 4
    for (int k = 0; k < 64; ++k) {
        float4 b = *(const float4*)&sB[k * 64 + c0];
        float bv[4] = {b.x, b.y, b.z, b.w};
        #pragma unroll
        for (int j = 0; j < 4; ++j) {
            float a = sA[(r0 + j) * 64 + k];
            #pragma unroll
            for (int i = 0; i < 4; ++i) acc[j][i] = fmaf(a, bv[i], acc[j][i]);
        }
    }
}

__global__ __launch_bounds__(256)
void prep_small(const float* __restrict__ Q,
                const float* __restrict__ Wq, const float* __restrict__ bq,
                const float* __restrict__ We, const float* __restrict__ be,
                const float* __restrict__ Wr, const float* __restrict__ br,
                const float* __restrict__ W1, const float* __restrict__ b1,
                const float* __restrict__ W2, char* __restrict__ wsb)
{
    __shared__ float sA[4096], sB[4096], sC[4096], sBias[64];
    const int t = threadIdx.x;
    const int bid = blockIdx.x;
    const int r0 = (t >> 4) * 4, c0 = (t & 15) * 4;

    if (bid == 0) {
        // Wqq = Wq@W1[0:64]; qc = Q@Wqq + (b1 + bq@W1q + be@(W1h+W1t) + br@W1r)
        stage64(sA, Wq, t); stage64(sB, W1, t);
        __syncthreads();
        float acc[4][4];
        gemm64(sA, sB, t, acc);
        #pragma unroll
        for (int j = 0; j < 4; ++j)
            *(float4*)&sC[(r0 + j) * 64 + c0] = make_float4(acc[j][0], acc[j][1], acc[j][2], acc[j][3]);
        if (t < 64) {
            float s = b1[t];
            for (int k = 0; k < 64; ++k) {
                s = fmaf(bq[k], W1[k * 64 + t], s);
                s = fmaf(be[k], W1[(64 + k) * 64 + t] + W1[(192 + k) * 64 + t], s);
                s = fmaf(br[k], W1[(128 + k) * 64 + t], s);
            }
            sBias[t] = s;
        }
        __syncthreads();
        stage64(sA, Q, t);
        __syncthreads();
        gemm64(sA, sC, t, acc);
        ushort* qcb = (ushort*)(wsb + WB_QCB);
        #pragma unroll
        for (int j = 0; j < 4; ++j) {
            ushort4 p;
            p.x = f2b(acc[j][0] + sBias[c0 + 0]);
            p.y = f2b(acc[j][1] + sBias[c0 + 1]);
            p.z = f2b(acc[j][2] + sBias[c0 + 2]);
            p.w = f2b(acc[j][3] + sBias[c0 + 3]);
            *(ushort4*)&qcb[(r0 + j) * 64 + c0] = p;
        }
    } else if (bid == 1 || bid == 2) {
        // Weh / Wet (fp32, consumed by prep_nodes)
        const float* w1seg = W1 + (bid == 1 ? 64 * 64 : 192 * 64);
        float* dst = (float*)(wsb + (bid == 1 ? WB_WEH : WB_WET));
        stage64(sA, We, t); stage64(sB, w1seg, t);
        __syncthreads();
        float acc[4][4];
        gemm64(sA, sB, t, acc);
        #pragma unroll
        for (int j = 0; j < 4; ++j)
            *(float4*)&dst[(r0 + j) * 64 + c0] = make_float4(acc[j][0], acc[j][1], acc[j][2], acc[j][3]);
    } else if (bid == 3) {
        // WrT = (Wr@W1r)^T, bf16
        stage64(sA, Wr, t); stage64(sB, W1 + 128 * 64, t);
        __syncthreads();
        float acc[4][4];
        gemm64(sA, sB, t, acc);
        ushort* wrtb = (ushort*)(wsb + WB_WRTB);
        #pragma unroll
        for (int j = 0; j < 4; ++j)
            #pragma unroll
            for (int i = 0; i < 4; ++i)
                wrtb[(c0 + i) * 64 + (r0 + j)] = f2b(acc[j][i]);
    } else {
        // W2^T bf16
        ushort* w2tb = (ushort*)(wsb + WB_W2TB);
        #pragma unroll
        for (int i = 0; i < 32; ++i) {
            int f = t + i * 256;           // f < 8192
            int k = f >> 7, n = f & 127;
            w2tb[n * 64 + k] = f2b(W2[f]);
        }
    }
}

__global__ __launch_bounds__(256)
void prep_nodes(const float* __restrict__ Xn, const char* __restrict__ wsb_c,
                char* __restrict__ wsb)
{
    __shared__ float sXT[64 * 68];
    __shared__ float sWeh[4096], sWet[4096];
    const int t = threadIdx.x;
    const int nbase = blockIdx.x * 64;
    const float* Weh = (const float*)(wsb_c + WB_WEH);
    const float* Wet = (const float*)(wsb_c + WB_WET);
    ushort* nhb = (ushort*)(wsb + WB_NHB);
    ushort* ntb = (ushort*)(wsb + WB_NTB);

    #pragma unroll
    for (int i = 0; i < 4; ++i) {
        int f = t + i * 256;
        int n = f >> 4, s4 = (f & 15) * 4;
        int gn = nbase + n;
        float4 v = make_float4(0.f, 0.f, 0.f, 0.f);
        if (gn < NNODE) v = *(const float4*)&Xn[gn * 64 + s4];
        sXT[(s4 + 0) * 68 + n] = v.x;
        sXT[(s4 + 1) * 68 + n] = v.y;
        sXT[(s4 + 2) * 68 + n] = v.z;
        sXT[(s4 + 3) * 68 + n] = v.w;
    }
    #pragma unroll
    for (int i = 0; i < 4; ++i) {
        int f = t + i * 256;
        *(float4*)&sWeh[f * 4] = *(const float4*)&Weh[f * 4];
        *(float4*)&sWet[f * 4] = *(const float4*)&Wet[f * 4];
    }
    __syncthreads();

    const int er = (t >> 4) * 4, cc = (t & 15) * 4;
    float ah[4][4], at[4][4];
    #pragma unroll
    for (int j = 0; j < 4; ++j)
        #pragma unroll
        for (int i = 0; i < 4; ++i) { ah[j][i] = 0.f; at[j][i] = 0.f; }
    #pragma unroll 4
    for (int k = 0; k < 64; ++k) {
        float4 a  = *(const float4*)&sXT[k * 68 + er];
        float4 bh = *(const float4*)&sWeh[k * 64 + cc];
        float4 bt = *(const float4*)&sWet[k * 64 + cc];
        float av[4] = {a.x, a.y, a.z, a.w};
        #pragma unroll
        for (int j = 0; j < 4; ++j) {
            ah[j][0] = fmaf(av[j], bh.x, ah[j][0]); ah[j][1] = fmaf(av[j], bh.y, ah[j][1]);
            ah[j][2] = fmaf(av[j], bh.z, ah[j][2]); ah[j][3] = fmaf(av[j], bh.w, ah[j][3]);
            at[j][0] = fmaf(av[j], bt.x, at[j][0]); at[j][1] = fmaf(av[j], bt.y, at[j][1]);
            at[j][2] = fmaf(av[j], bt.z, at[j][2]); at[j][3] = fmaf(av[j], bt.w, at[j][3]);
        }
    }
    #pragma unroll
    for (int j = 0; j < 4; ++j) {
        int n = nbase + er + j;
        if (n < NNODE) {
            uint2 ph, pt;
            ph.x = cvtpk(ah[j][0], ah[j][1]); ph.y = cvtpk(ah[j][2], ah[j][3]);
            pt.x = cvtpk(at[j][0], at[j][1]); pt.y = cvtpk(at[j][2], at[j][3]);
            *(uint2*)&nhb[n * 64 + cc] = ph;
            *(uint2*)&ntb[n * 64 + cc] = pt;
        }
    }
}

// R6 structure (weights in LDS, 3 blocks/CU, wave-local barrier-free tile
// loop) + INDEX HOISTING: all EI/NB index loads for all 4 tiles issue at
// block start (8 parallel loads + 1 dependent NB level, once per block).
// Per-tile prefetch is then a 1-deep chain (table gathers + Xe), which
// fits under one tile's compute — the 3-deep EI->NB->table chain no
// longer sits on the steady-state critical path.
#define TILES_PER_BLK 4

__global__ __launch_bounds__(256, 3)
void edge_kernel(const float* __restrict__ Xe,
                 const int* __restrict__ EI,
                 const int* __restrict__ NB,
                 const float* __restrict__ b2,
                 const float* __restrict__ Wh,
                 const float* __restrict__ bh,
                 const char* __restrict__ wsb,
                 float* __restrict__ out)
{
    __shared__ ushort sX[64 * 72];     // X tile bf16; reused as H1 bf16 (wave-local rows)
    __shared__ ushort sWr[64 * 72];    // Wr'^T bf16 rows n  (read-only after stage)
    __shared__ ushort sW2[128 * 72];   // W2^T bf16 rows n   (read-only after stage)
    __shared__ ushort sG[64 * 72];     // gathered additive term, bf16 (wave-local rows)

    const int t = threadIdx.x;
    const ushort* qcb  = (const ushort*)(wsb + WB_QCB);
    const ushort* wrtb = (const ushort*)(wsb + WB_WRTB);
    const ushort* w2tb = (const ushort*)(wsb + WB_W2TB);
    const ushort* nhb  = (const ushort*)(wsb + WB_NHB);
    const ushort* ntb  = (const ushort*)(wsb + WB_NTB);

    const int lane = t & 63;
    const int w    = t >> 6;           // wave id = M-tile
    const int m    = lane & 15;
    const int qq   = lane >> 4;
    const int q8   = qq * 8;

    const int eg  = t >> 2;            // gather role: edge in tile (in [16w,16w+16))
    const int c0g = (t & 3) * 16;      // 16-col slice
    const int xrow = 16 * w + (lane >> 2);   // X-stage role: row (wave-local!)
    const int xsl  = lane & 3;               // float4-slice base

    const int ebase0 = blockIdx.x * (64 * TILES_PER_BLK);

    // ---- index hoist: ALL tiles' gather indices resolved at block start ----
    int hdA[TILES_PER_BLK], tlA[TILES_PER_BLK], qiA[TILES_PER_BLK];
    #pragma unroll
    for (int tt = 0; tt < TILES_PER_BLK; ++tt) {
        hdA[tt] = EI[ebase0 + tt * 64 + eg];
        tlA[tt] = EI[NEDGE + ebase0 + tt * 64 + eg];
    }
    #pragma unroll
    for (int tt = 0; tt < TILES_PER_BLK; ++tt) qiA[tt] = NB[hdA[tt]];

    // ---- weights: global -> LDS, ONCE per block ----
    {
        uint4 wrl[2], w2l[4];
        #pragma unroll
        for (int i = 0; i < 2; ++i) {
            int f = t + i * 256;
            wrl[i] = *(const uint4*)&wrtb[(f >> 3) * 64 + (f & 7) * 8];
        }
        #pragma unroll
        for (int i = 0; i < 4; ++i) {
            int f = t + i * 256;
            w2l[i] = *(const uint4*)&w2tb[(f >> 3) * 64 + (f & 7) * 8];
        }
        #pragma unroll
        for (int i = 0; i < 2; ++i) {
            int f = t + i * 256;
            *(uint4*)&sWr[(f >> 3) * 72 + (f & 7) * 8] = wrl[i];
        }
        #pragma unroll
        for (int i = 0; i < 4; ++i) {
            int f = t + i * 256;
            *(uint4*)&sW2[(f >> 3) * 72 + (f & 7) * 8] = w2l[i];
        }
    }
    // per-lane bias/head weights in registers (constant per block)
    float b2v[8], whv[8];
    #pragma unroll
    for (int nt = 0; nt < 8; ++nt) {
        b2v[nt] = b2[nt * 16 + m];
        whv[nt] = Wh[nt * 16 + m];
    }
    const float bh0 = bh[0];

    __syncthreads();   // the ONLY block barrier: weight LDS visible to all waves

    // per-tile load: 1-deep table gathers (indices pre-resolved) + Xe rows
    auto load_tile = [&](int tt, uint4* g, float4* x) {
        const int hd = hdA[tt], tl = tlA[tt], qi = qiA[tt];
        g[0] = *(const uint4*)&qcb[qi * 64 + c0g];
        g[1] = *(const uint4*)&qcb[qi * 64 + c0g + 8];
        g[2] = *(const uint4*)&nhb[hd * 64 + c0g];
        g[3] = *(const uint4*)&nhb[hd * 64 + c0g + 8];
        g[4] = *(const uint4*)&ntb[tl * 64 + c0g];
        g[5] = *(const uint4*)&ntb[tl * 64 + c0g + 8];
        const int eb = ebase0 + tt * 64;
        #pragma unroll
        for (int i = 0; i < 4; ++i)
            x[i] = *(const float4*)&Xe[(eb + xrow) * 64 + (xsl + 4 * i) * 4];
    };

    uint4  g[6];  float4 x[4];
    uint4  ng[6]; float4 nx[4];
    load_tile(0, g, x);

    #pragma unroll
    for (int tile = 0; tile < TILES_PER_BLK; ++tile) {
        // ---- gather-sum -> sG (wave-local rows; no barrier needed) ----
        {
            uint pk[8];
            const uint* ua = (const uint*)&g[0];
            const uint* ub = (const uint*)&g[2];
            const uint* uc = (const uint*)&g[4];
            #pragma unroll
            for (int j = 0; j < 4; ++j) {
                float lo = bLo(ua[j]) + bLo(ub[j]) + bLo(uc[j]);
                float hi = bHi(ua[j]) + bHi(ub[j]) + bHi(uc[j]);
                pk[j] = cvtpk(lo, hi);
            }
            ua = (const uint*)&g[1]; ub = (const uint*)&g[3]; uc = (const uint*)&g[5];
            #pragma unroll
            for (int j = 0; j < 4; ++j) {
                float lo = bLo(ua[j]) + bLo(ub[j]) + bLo(uc[j]);
                float hi = bHi(ua[j]) + bHi(ub[j]) + bHi(uc[j]);
                pk[4 + j] = cvtpk(lo, hi);
            }
            *(uint4*)&sG[eg * 72 + c0g]     = make_uint4(pk[0], pk[1], pk[2], pk[3]);
            *(uint4*)&sG[eg * 72 + c0g + 8] = make_uint4(pk[4], pk[5], pk[6], pk[7]);
        }
        // ---- X -> bf16 LDS (wave-local rows, stride 72) ----
        #pragma unroll
        for (int i = 0; i < 4; ++i) {
            uint lo = cvtpk(x[i].x, x[i].y);
            uint hi = cvtpk(x[i].z, x[i].w);
            *(uint2*)&sX[xrow * 72 + (xsl + 4 * i) * 4] = make_uint2(lo, hi);
        }
        // ---- prefetch next tile: 1-deep loads, hidden under MFMA phases ----
        if (tile < TILES_PER_BLK - 1) load_tile(tile + 1, ng, nx);

        // ---- h1 = relu(X@Wr' + g); write back into sX (same-wave RAW, in-order DS) ----
        bf16x8 a0 = *(const bf16x8*)&sX[(w * 16 + m) * 72 + q8];
        bf16x8 a1 = *(const bf16x8*)&sX[(w * 16 + m) * 72 + 32 + q8];
        f32x4 acc1[4];
        #pragma unroll
        for (int nt = 0; nt < 4; ++nt) {
            bf16x8 b0  = *(const bf16x8*)&sWr[(nt * 16 + m) * 72 + q8];
            bf16x8 b1v = *(const bf16x8*)&sWr[(nt * 16 + m) * 72 + 32 + q8];
            f32x4 c = {0.f, 0.f, 0.f, 0.f};
            c = __builtin_amdgcn_mfma_f32_16x16x32_bf16(a0, b0, c, 0, 0, 0);
            c = __builtin_amdgcn_mfma_f32_16x16x32_bf16(a1, b1v, c, 0, 0, 0);
            acc1[nt] = c;
        }
        #pragma unroll
        for (int nt = 0; nt < 4; ++nt) {
            int c = nt * 16 + m;
            const int e0 = w * 16 + qq * 4;
            float v0 = fmaxf(acc1[nt][0] + __uint_as_float(((uint)sG[(e0 + 0) * 72 + c]) << 16), 0.f);
            float v1 = fmaxf(acc1[nt][1] + __uint_as_float(((uint)sG[(e0 + 1) * 72 + c]) << 16), 0.f);
            float v2 = fmaxf(acc1[nt][2] + __uint_as_float(((uint)sG[(e0 + 2) * 72 + c]) << 16), 0.f);
            float v3 = fmaxf(acc1[nt][3] + __uint_as_float(((uint)sG[(e0 + 3) * 72 + c]) << 16), 0.f);
            uint p01 = cvtpk(v0, v1);
            uint p23 = cvtpk(v2, v3);
            sX[(e0 + 0) * 72 + c] = (ushort)p01;
            sX[(e0 + 1) * 72 + c] = (ushort)(p01 >> 16);
            sX[(e0 + 2) * 72 + c] = (ushort)p23;
            sX[(e0 + 3) * 72 + c] = (ushort)(p23 >> 16);
        }

        // ---- h2 = relu(H1@W2 + b2); logit = h2@Wh + bh ----
        bf16x8 A0 = *(const bf16x8*)&sX[(w * 16 + m) * 72 + q8];
        bf16x8 A1 = *(const bf16x8*)&sX[(w * 16 + m) * 72 + 32 + q8];
        float part[4] = {0.f, 0.f, 0.f, 0.f};
        #pragma unroll
        for (int nt = 0; nt < 8; ++nt) {
            bf16x8 B0 = *(const bf16x8*)&sW2[(nt * 16 + m) * 72 + q8];
            bf16x8 B1 = *(const bf16x8*)&sW2[(nt * 16 + m) * 72 + 32 + q8];
            f32x4 c = {0.f, 0.f, 0.f, 0.f};
            c = __builtin_amdgcn_mfma_f32_16x16x32_bf16(A0, B0, c, 0, 0, 0);
            c = __builtin_amdgcn_mfma_f32_16x16x32_bf16(A1, B1, c, 0, 0, 0);
            #pragma unroll
            for (int r = 0; r < 4; ++r)
                part[r] = fmaf(fmaxf(c[r] + b2v[nt], 0.f), whv[nt], part[r]);
        }
        #pragma unroll
        for (int md = 1; md < 16; md <<= 1) {
            part[0] += __shfl_xor(part[0], md, 64);
            part[1] += __shfl_xor(part[1], md, 64);
            part[2] += __shfl_xor(part[2], md, 64);
            part[3] += __shfl_xor(part[3], md, 64);
        }
        if (m == 0) {
            float4 o;
            o.x = 1.f / (1.f + __expf(-(part[0] + bh0)));
            o.y = 1.f / (1.f + __expf(-(part[1] + bh0)));
            o.z = 1.f / (1.f + __expf(-(part[2] + bh0)));
            o.w = 1.f / (1.f + __expf(-(part[3] + bh0)));
            *(float4*)&out[ebase0 + tile * 64 + w * 16 + qq * 4] = o;
        }

        if (tile < TILES_PER_BLK - 1) {
            #pragma unroll
            for (int i = 0; i < 6; ++i) g[i] = ng[i];
            #pragma unroll
            for (int i = 0; i < 4; ++i) x[i] = nx[i];
        }
    }
}

extern "C" void kernel_launch(void* const* d_in, const int* in_sizes, int n_in,
                              void* d_out, int out_size, void* d_ws, size_t ws_size,
                              hipStream_t stream)
{
    const float* Q   = (const float*)d_in[0];
    const float* Xn  = (const float*)d_in[1];
    const float* Xe  = (const float*)d_in[2];
    const int*   EI  = (const int*)d_in[3];
    const int*   NB  = (const int*)d_in[4];
    const float* Wq  = (const float*)d_in[5];
    const float* bq  = (const float*)d_in[6];
    const float* We  = (const float*)d_in[7];
    const float* be  = (const float*)d_in[8];
    const float* Wr  = (const float*)d_in[9];
    const float* br  = (const float*)d_in[10];
    const float* W1  = (const float*)d_in[11];
    const float* b1  = (const float*)d_in[12];
    const float* W2  = (const float*)d_in[13];
    const float* b2  = (const float*)d_in[14];
    const float* Wh  = (const float*)d_in[15];
    const float* bh  = (const float*)d_in[16];
    float* out = (float*)d_out;
    char*  wsb = (char*)d_ws;

    prep_small<<<5, 256, 0, stream>>>(Q, Wq, bq, We, be, Wr, br, W1, b1, W2, wsb);
    prep_nodes<<<(NNODE + 63) / 64, 256, 0, stream>>>(Xn, wsb, wsb);
    edge_kernel<<<NEDGE / (64 * TILES_PER_BLK), 256, 0, stream>>>(Xe, EI, NB, b2, Wh, bh, wsb, out);
}